// Round 2
// baseline (156.129 us; speedup 1.0000x reference)
//
#include <hip/hip_runtime.h>
#include <stdint.h>

// Problem constants
#define B_   4
#define H_   56
#define W_   56
#define C_   256
#define CR   64
#define G_   16
#define CG   16
#define KS   7
#define KK   49
#define PADR 3
#define NPX  (B_*H_*W_)   // 12544

// ---------- K0: fold BN into per-channel scale/shift ----------
__global__ __launch_bounds__(64) void k0_bn(
        const float* __restrict__ gamma, const float* __restrict__ beta,
        const float* __restrict__ mean, const float* __restrict__ var,
        float* __restrict__ scale_f, float* __restrict__ shift_f) {
    int i = threadIdx.x;
    if (i < CR) {
        float s = gamma[i] * rsqrtf(var[i] + 1e-3f);
        scale_f[i] = s;
        shift_f[i] = beta[i] - mean[i] * s;
    }
}

// ---------- K1: r = relu(bn(x @ w_reduce)), fp32, (NPX, 64) ----------
__global__ __launch_bounds__(256) void k1_reduce(
        const float* __restrict__ x, const float* __restrict__ wr,
        const float* __restrict__ scale_f, const float* __restrict__ shift_f,
        float* __restrict__ r) {
    int tid = threadIdx.x;
    int d = tid & 63;                               // output channel (lane)
    int q = tid >> 6;                               // wave id: 4 waves/block
    int px0 = blockIdx.x * 16 + q * 4;              // 4 pixels per wave
    const float* xr = x + (size_t)px0 * C_;
    float a0 = 0.f, a1 = 0.f, a2 = 0.f, a3 = 0.f;
    for (int c4 = 0; c4 < C_ / 4; ++c4) {
        // x rows are wave-uniform -> scalar s_load_dwordx4
        float4 x0 = *(const float4*)(xr + 0*C_ + c4*4);
        float4 x1 = *(const float4*)(xr + 1*C_ + c4*4);
        float4 x2 = *(const float4*)(xr + 2*C_ + c4*4);
        float4 x3 = *(const float4*)(xr + 3*C_ + c4*4);
        const float* p0 = (const float*)&x0;
        const float* p1 = (const float*)&x1;
        const float* p2 = (const float*)&x2;
        const float* p3 = (const float*)&x3;
        #pragma unroll
        for (int j = 0; j < 4; ++j) {
            float wv = wr[(c4*4 + j) * CR + d];     // coalesced across lanes
            a0 = fmaf(wv, p0[j], a0);
            a1 = fmaf(wv, p1[j], a1);
            a2 = fmaf(wv, p2[j], a2);
            a3 = fmaf(wv, p3[j], a3);
        }
    }
    float s = scale_f[d], sh = shift_f[d];
    float r0 = fmaf(a0, s, sh); r0 = r0 > 0.f ? r0 : 0.f;
    float r1 = fmaf(a1, s, sh); r1 = r1 > 0.f ? r1 : 0.f;
    float r2 = fmaf(a2, s, sh); r2 = r2 > 0.f ? r2 : 0.f;
    float r3 = fmaf(a3, s, sh); r3 = r3 > 0.f ? r3 : 0.f;
    r[(size_t)(px0 + 0) * CR + d] = r0;
    r[(size_t)(px0 + 1) * CR + d] = r1;
    r[(size_t)(px0 + 2) * CR + d] = r2;
    r[(size_t)(px0 + 3) * CR + d] = r3;
}

// ---------- K2: kgen + involution, one block per (tile, group, batch) ----------
#define TS   14           // output tile edge
#define HS   20           // TS + KS - 1 (halo)
#define XSTR 20           // fp32 stride per position in LDS (16 ch + pad; 2-way conflicts = free)

__global__ __launch_bounds__(256) void k2_involution(
        const float* __restrict__ x, const float* __restrict__ r,
        const float* __restrict__ wspan, const float* __restrict__ bspan,
        float* __restrict__ out) {
    __shared__ float xs[HS * HS * XSTR];   // 8000 floats = 32 KB

    int tid  = threadIdx.x;
    int tile = blockIdx.x;          // 0..15 -> 4x4 tiles of 14x14
    int g    = blockIdx.y;          // 0..15
    int b    = blockIdx.z;          // 0..3
    int ty0 = (tile >> 2) * TS;
    int tx0 = (tile & 3) * TS;

    // ---- stage x group-slice tile (with halo) into LDS ----
    for (int i = tid; i < HS * HS; i += 256) {
        int py = i / HS, px = i % HS;
        int gy = ty0 + py - PADR, gx = tx0 + px - PADR;
        float4 v0, v1, v2, v3;
        if (gy >= 0 && gy < H_ && gx >= 0 && gx < W_) {
            const float* xp = x + (((size_t)(b * H_ + gy)) * W_ + gx) * C_ + g * CG;
            v0 = *(const float4*)(xp + 0);
            v1 = *(const float4*)(xp + 4);
            v2 = *(const float4*)(xp + 8);
            v3 = *(const float4*)(xp + 12);
        } else {
            v0 = v1 = v2 = v3 = make_float4(0.f, 0.f, 0.f, 0.f);
        }
        float* dst = xs + i * XSTR;
        *(float4*)(dst + 0)  = v0;
        *(float4*)(dst + 4)  = v1;
        *(float4*)(dst + 8)  = v2;
        *(float4*)(dst + 12) = v3;
    }
    __syncthreads();

    if (tid >= TS * TS) return;     // no further barriers below
    int ty = tid / TS, tx = tid % TS;
    int hy = ty0 + ty, hx = tx0 + tx;
    size_t pix = ((size_t)(b * H_ + hy)) * W_ + hx;

    // ---- kgen: kg[kk] = b_span[g*49+kk] + sum_d r[pix,d] * w_span[d, g*49+kk] ----
    float kg[KK];
    const float* bs = bspan + g * KK;                // wave-uniform -> s_load
    #pragma unroll
    for (int kk = 0; kk < KK; ++kk) kg[kk] = bs[kk];

    const float4* rp4 = (const float4*)(r + pix * CR);
    const float*  wsg = wspan + g * KK;              // wave-uniform rows
    for (int d4 = 0; d4 < CR / 4; ++d4) {
        float4 rv = rp4[d4];
        const float* w0 = wsg + (d4 * 4 + 0) * (KK * G_);
        const float* w1 = wsg + (d4 * 4 + 1) * (KK * G_);
        const float* w2 = wsg + (d4 * 4 + 2) * (KK * G_);
        const float* w3 = wsg + (d4 * 4 + 3) * (KK * G_);
        #pragma unroll
        for (int kk = 0; kk < KK; ++kk) kg[kk] = fmaf(rv.x, w0[kk], kg[kk]);
        #pragma unroll
        for (int kk = 0; kk < KK; ++kk) kg[kk] = fmaf(rv.y, w1[kk], kg[kk]);
        #pragma unroll
        for (int kk = 0; kk < KK; ++kk) kg[kk] = fmaf(rv.z, w2[kk], kg[kk]);
        #pragma unroll
        for (int kk = 0; kk < KK; ++kk) kg[kk] = fmaf(rv.w, w3[kk], kg[kk]);
    }

    // ---- involution: acc[c] = sum_kk kg[kk] * xs[(ty+kh)(tx+kw)][c] ----
    float acc[CG];
    #pragma unroll
    for (int c = 0; c < CG; ++c) acc[c] = 0.f;
    #pragma unroll
    for (int kh = 0; kh < KS; ++kh) {
        #pragma unroll
        for (int kw = 0; kw < KS; ++kw) {
            float kv = kg[kh * KS + kw];
            const float* xp = xs + ((ty + kh) * HS + (tx + kw)) * XSTR;
            #pragma unroll
            for (int c4 = 0; c4 < 4; ++c4) {
                float4 xv = *(const float4*)(xp + c4 * 4);
                acc[c4*4 + 0] = fmaf(kv, xv.x, acc[c4*4 + 0]);
                acc[c4*4 + 1] = fmaf(kv, xv.y, acc[c4*4 + 1]);
                acc[c4*4 + 2] = fmaf(kv, xv.z, acc[c4*4 + 2]);
                acc[c4*4 + 3] = fmaf(kv, xv.w, acc[c4*4 + 3]);
            }
        }
    }

    // ---- store 16 fp32 (64 B, aligned) ----
    float* op = out + pix * C_ + g * CG;
    *(float4*)(op + 0)  = make_float4(acc[0],  acc[1],  acc[2],  acc[3]);
    *(float4*)(op + 4)  = make_float4(acc[4],  acc[5],  acc[6],  acc[7]);
    *(float4*)(op + 8)  = make_float4(acc[8],  acc[9],  acc[10], acc[11]);
    *(float4*)(op + 12) = make_float4(acc[12], acc[13], acc[14], acc[15]);
}

extern "C" void kernel_launch(void* const* d_in, const int* in_sizes, int n_in,
                              void* d_out, int out_size, void* d_ws, size_t ws_size,
                              hipStream_t stream) {
    const float* x        = (const float*)d_in[0];
    const float* w_reduce = (const float*)d_in[1];
    const float* gamma    = (const float*)d_in[2];
    const float* beta     = (const float*)d_in[3];
    const float* mean     = (const float*)d_in[4];
    const float* var      = (const float*)d_in[5];
    const float* w_span   = (const float*)d_in[6];
    const float* b_span   = (const float*)d_in[7];
    float* out = (float*)d_out;

    float* ws      = (float*)d_ws;
    float* r_ws    = ws;                         // 802816 floats (3.2 MB)
    float* scale_f = ws + 802816;                // 64
    float* shift_f = ws + 802880;                // 64

    hipLaunchKernelGGL(k0_bn, dim3(1), dim3(64), 0, stream,
                       gamma, beta, mean, var, scale_f, shift_f);
    hipLaunchKernelGGL(k1_reduce, dim3(NPX / 16), dim3(256), 0, stream,
                       x, w_reduce, scale_f, shift_f, r_ws);
    hipLaunchKernelGGL(k2_involution, dim3(16, 16, B_), dim3(256), 0, stream,
                       x, r_ws, w_span, b_span, out);
}

// Round 3
// 105.713 us; speedup vs baseline: 1.4769x; 1.4769x over previous
//
#include <hip/hip_runtime.h>
#include <stdint.h>

#define B_   4
#define H_   56
#define W_   56
#define C_   256
#define CR   64
#define G_   16
#define CG   16
#define KS   7
#define KK   49
#define PADR 3
#define NPX  (B_*H_*W_)   // 12544

typedef __attribute__((ext_vector_type(8))) short bf16x8;
typedef __attribute__((ext_vector_type(4))) float f32x4;

__device__ __forceinline__ uint32_t f2bf(float f) {          // RNE fp32->bf16 bits
    uint32_t x = __float_as_uint(f);
    return (x + 0x7fffu + ((x >> 16) & 1u)) >> 16;
}
__device__ __forceinline__ float bf2f(uint32_t u) {
    return __uint_as_float(u << 16);
}

// ---------- K0: prepack weights into MFMA B-frag layout (bf16), fold BN ----------
// B-frag for mfma_f32_16x16x32_bf16: lane holds B[k=(lane>>4)*8+j][n=lane&15], j=0..7
__global__ __launch_bounds__(256) void k0_prepack(
        const float* __restrict__ wr, const float* __restrict__ wspan,
        const float* __restrict__ gamma, const float* __restrict__ beta,
        const float* __restrict__ mean, const float* __restrict__ var,
        uint16_t* __restrict__ wrp, uint16_t* __restrict__ wpp,
        float* __restrict__ scale, float* __restrict__ shift) {
    int idx = blockIdx.x * 256 + threadIdx.x;   // 0..65535
    {   // w_span pack: idx = g*4096 + kb*2048 + nb*512 + lane*8 + j
        int j = idx & 7, lane = (idx >> 3) & 63, nb = (idx >> 9) & 3,
            kb = (idx >> 11) & 1, g = idx >> 12;
        int k = kb * 32 + (lane >> 4) * 8 + j;
        int n = nb * 16 + (lane & 15);
        float v = (n < KK) ? wspan[k * (KK * G_) + g * KK + n] : 0.f;
        wpp[idx] = (uint16_t)f2bf(v);
    }
    if (idx < 16384) {  // w_reduce pack: idx = kb*2048 + nb*512 + lane*8 + j
        int j = idx & 7, lane = (idx >> 3) & 63, nb = (idx >> 9) & 3, kb = idx >> 11;
        int k = kb * 32 + (lane >> 4) * 8 + j;
        int n = nb * 16 + (lane & 15);
        wrp[idx] = (uint16_t)f2bf(wr[k * CR + n]);
    }
    if (idx < CR) {
        float s = gamma[idx] * rsqrtf(var[idx] + 1e-3f);
        scale[idx] = s;
        shift[idx] = beta[idx] - mean[idx] * s;
    }
}

// ---------- K1: r = relu(bn(x @ w_reduce)) via MFMA, r stored bf16 row-major ----------
__global__ __launch_bounds__(64) void k1_reduce(
        const float* __restrict__ x, const uint16_t* __restrict__ wrp,
        const float* __restrict__ scale, const float* __restrict__ shift,
        uint16_t* __restrict__ r) {
    int lane = threadIdx.x;
    int mt = blockIdx.x;                         // 784 row-tiles of 16 pixels
    int pix = mt * 16 + (lane & 15);             // A-frag: m = lane&15
    const float* xrow = x + (size_t)pix * C_ + (lane >> 4) * 8;
    f32x4 acc[4] = {{0,0,0,0},{0,0,0,0},{0,0,0,0},{0,0,0,0}};
    for (int kb = 0; kb < 8; ++kb) {             // K = 256 in steps of 32
        float4 a0 = *(const float4*)(xrow + kb * 32);
        float4 a1 = *(const float4*)(xrow + kb * 32 + 4);
        bf16x8 af;
        af[0] = (short)f2bf(a0.x); af[1] = (short)f2bf(a0.y);
        af[2] = (short)f2bf(a0.z); af[3] = (short)f2bf(a0.w);
        af[4] = (short)f2bf(a1.x); af[5] = (short)f2bf(a1.y);
        af[6] = (short)f2bf(a1.z); af[7] = (short)f2bf(a1.w);
        const uint16_t* wb = wrp + kb * 2048 + lane * 8;
        #pragma unroll
        for (int nb = 0; nb < 4; ++nb) {
            bf16x8 bf_ = *(const bf16x8*)(wb + nb * 512);
            acc[nb] = __builtin_amdgcn_mfma_f32_16x16x32_bf16(af, bf_, acc[nb], 0, 0, 0);
        }
    }
    // C layout: col=lane&15 (channel within nb), row=(lane>>4)*4+reg (pixel)
    int rq = (lane >> 4) * 4;
    #pragma unroll
    for (int nb = 0; nb < 4; ++nb) {
        int d = nb * 16 + (lane & 15);
        float s = scale[d], sh = shift[d];
        #pragma unroll
        for (int rg = 0; rg < 4; ++rg) {
            float v = fmaf(acc[nb][rg], s, sh);
            v = v > 0.f ? v : 0.f;
            r[(size_t)(mt * 16 + rq + rg) * CR + d] = (uint16_t)f2bf(v);
        }
    }
}

// ---------- K2: kgen (MFMA) + involution, one block per (tile, group, batch) ----------
#define TS    14        // output tile edge
#define HS    20        // TS + KS - 1
#define XP    20        // fp32 per position in LDS (16 ch + 4 pad)
#define ROWS  404       // fp32 per halo row (20*XP + 4 pad): ty-step = 20 banks (odd quad)

__global__ __launch_bounds__(256, 3) void k2_involution(
        const float* __restrict__ x, const uint16_t* __restrict__ r,
        const uint16_t* __restrict__ wpp, const float* __restrict__ bspan,
        float* __restrict__ out) {
    __shared__ float    xs[HS * ROWS];      // 32320 B
    __shared__ uint16_t kg[208 * KK];       // 20384 B  (52.7 KB total -> 3 blocks/CU)

    int tid  = threadIdx.x;
    int tile = blockIdx.x, g = blockIdx.y, b = blockIdx.z;
    int ty0 = (tile >> 2) * TS, tx0 = (tile & 3) * TS;

    // ---- stage x group-slice (with halo) into LDS ----
    #pragma unroll
    for (int pass = 0; pass < 2; ++pass) {
        int i = tid + pass * 256;
        if (i < HS * HS) {
            int py = i / HS, px = i % HS;
            int gy = ty0 + py - PADR, gx = tx0 + px - PADR;
            float4 v0, v1, v2, v3;
            if (gy >= 0 && gy < H_ && gx >= 0 && gx < W_) {
                const float* xp = x + (((size_t)(b * H_ + gy)) * W_ + gx) * C_ + g * CG;
                v0 = *(const float4*)(xp + 0);
                v1 = *(const float4*)(xp + 4);
                v2 = *(const float4*)(xp + 8);
                v3 = *(const float4*)(xp + 12);
            } else {
                v0 = v1 = v2 = v3 = make_float4(0.f, 0.f, 0.f, 0.f);
            }
            float* dst = xs + py * ROWS + px * XP;
            *(float4*)(dst + 0)  = v0;
            *(float4*)(dst + 4)  = v1;
            *(float4*)(dst + 8)  = v2;
            *(float4*)(dst + 12) = v3;
        }
    }

    // ---- kgen via MFMA: kg(196x49) = r_tile(196x64) @ wspan_g(64x49) + bias ----
    int lane = tid & 63, w = tid >> 6;
    bf16x8 bfr[2][4];
    const uint16_t* wb = wpp + g * 4096 + lane * 8;
    #pragma unroll
    for (int kb = 0; kb < 2; ++kb)
        #pragma unroll
        for (int nb = 0; nb < 4; ++nb)
            bfr[kb][nb] = *(const bf16x8*)(wb + kb * 2048 + nb * 512);
    float bias[4];
    #pragma unroll
    for (int nb = 0; nb < 4; ++nb) {
        int n = nb * 16 + (lane & 15);
        bias[nb] = (n < KK) ? bspan[g * KK + n] : 0.f;
    }
    for (int mi = 0; mi < 4; ++mi) {
        int mt = mi * 4 + w;                    // 13 row-tiles over 4 waves
        if (mt < 13) {
            int m  = mt * 16 + (lane & 15);
            int mm = m < 196 ? m : 195;         // pad rows: load valid mem, ignored later
            int ly = mm / TS, lx = mm % TS;
            size_t pix = ((size_t)(b * H_ + ty0 + ly)) * W_ + (tx0 + lx);
            const uint16_t* rp = r + pix * CR + (lane >> 4) * 8;
            bf16x8 a0 = *(const bf16x8*)(rp);
            bf16x8 a1 = *(const bf16x8*)(rp + 32);
            f32x4 acc[4];
            #pragma unroll
            for (int nb = 0; nb < 4; ++nb)
                acc[nb] = (f32x4){bias[nb], bias[nb], bias[nb], bias[nb]};
            #pragma unroll
            for (int nb = 0; nb < 4; ++nb) {
                acc[nb] = __builtin_amdgcn_mfma_f32_16x16x32_bf16(a0, bfr[0][nb], acc[nb], 0, 0, 0);
                acc[nb] = __builtin_amdgcn_mfma_f32_16x16x32_bf16(a1, bfr[1][nb], acc[nb], 0, 0, 0);
            }
            #pragma unroll
            for (int nb = 0; nb < 4; ++nb) {
                int n = nb * 16 + (lane & 15);
                if (n < KK) {
                    int row = mt * 16 + (lane >> 4) * 4;
                    #pragma unroll
                    for (int rg = 0; rg < 4; ++rg)
                        kg[(row + rg) * KK + n] = (uint16_t)f2bf(acc[nb][rg]);
                }
            }
        }
    }
    __syncthreads();

    // ---- involution: 98 threads, 2 adjacent pixels each (window overlap -> fewer LDS reads) ----
    if (tid < 98) {
        int ty  = tid / 7;            // 0..13
        int tx2 = (tid % 7) * 2;      // 0,2,...,12
        float accL[CG], accR[CG];
        #pragma unroll
        for (int c = 0; c < CG; ++c) { accL[c] = 0.f; accR[c] = 0.f; }
        const uint16_t* kgL = kg + (ty * TS + tx2) * KK;
        const uint16_t* kgR = kgL + KK;
        for (int kh = 0; kh < KS; ++kh) {
            const float* xrow = xs + (ty + kh) * ROWS + tx2 * XP;
            #pragma unroll
            for (int p = 0; p < 8; ++p) {        // union of both 7-tap windows
                float kvL = 0.f, kvR = 0.f;
                if (p < 7) kvL = bf2f(kgL[kh * 7 + p]);
                if (p > 0) kvR = bf2f(kgR[kh * 7 + p - 1]);
                const float* xp = xrow + p * XP;
                #pragma unroll
                for (int c4 = 0; c4 < 4; ++c4) {
                    float4 xv = *(const float4*)(xp + c4 * 4);
                    if (p < 7) {
                        accL[c4*4+0] = fmaf(kvL, xv.x, accL[c4*4+0]);
                        accL[c4*4+1] = fmaf(kvL, xv.y, accL[c4*4+1]);
                        accL[c4*4+2] = fmaf(kvL, xv.z, accL[c4*4+2]);
                        accL[c4*4+3] = fmaf(kvL, xv.w, accL[c4*4+3]);
                    }
                    if (p > 0) {
                        accR[c4*4+0] = fmaf(kvR, xv.x, accR[c4*4+0]);
                        accR[c4*4+1] = fmaf(kvR, xv.y, accR[c4*4+1]);
                        accR[c4*4+2] = fmaf(kvR, xv.z, accR[c4*4+2]);
                        accR[c4*4+3] = fmaf(kvR, xv.w, accR[c4*4+3]);
                    }
                }
            }
        }
        size_t pixL = ((size_t)(b * H_ + ty0 + ty)) * W_ + (tx0 + tx2);
        float* opL = out + pixL * C_ + g * CG;
        float* opR = opL + C_;
        *(float4*)(opL + 0)  = make_float4(accL[0],  accL[1],  accL[2],  accL[3]);
        *(float4*)(opL + 4)  = make_float4(accL[4],  accL[5],  accL[6],  accL[7]);
        *(float4*)(opL + 8)  = make_float4(accL[8],  accL[9],  accL[10], accL[11]);
        *(float4*)(opL + 12) = make_float4(accL[12], accL[13], accL[14], accL[15]);
        *(float4*)(opR + 0)  = make_float4(accR[0],  accR[1],  accR[2],  accR[3]);
        *(float4*)(opR + 4)  = make_float4(accR[4],  accR[5],  accR[6],  accR[7]);
        *(float4*)(opR + 8)  = make_float4(accR[8],  accR[9],  accR[10], accR[11]);
        *(float4*)(opR + 12) = make_float4(accR[12], accR[13], accR[14], accR[15]);
    }
}

extern "C" void kernel_launch(void* const* d_in, const int* in_sizes, int n_in,
                              void* d_out, int out_size, void* d_ws, size_t ws_size,
                              hipStream_t stream) {
    const float* x        = (const float*)d_in[0];
    const float* w_reduce = (const float*)d_in[1];
    const float* gamma    = (const float*)d_in[2];
    const float* beta     = (const float*)d_in[3];
    const float* mean     = (const float*)d_in[4];
    const float* var      = (const float*)d_in[5];
    const float* w_span   = (const float*)d_in[6];
    const float* b_span   = (const float*)d_in[7];
    float* out = (float*)d_out;

    uint8_t* ws = (uint8_t*)d_ws;
    uint16_t* r_ws  = (uint16_t*)(ws + 0);          // 1605632 B
    uint16_t* wrp   = (uint16_t*)(ws + 1605632);    // 32768 B
    uint16_t* wpp   = (uint16_t*)(ws + 1638400);    // 131072 B
    float*    scale = (float*)   (ws + 1769472);    // 256 B
    float*    shift = (float*)   (ws + 1769728);    // 256 B

    hipLaunchKernelGGL(k0_prepack, dim3(256), dim3(256), 0, stream,
                       w_reduce, w_span, gamma, beta, mean, var,
                       wrp, wpp, scale, shift);
    hipLaunchKernelGGL(k1_reduce, dim3(NPX / 16), dim3(64), 0, stream,
                       x, wrp, scale, shift, r_ws);
    hipLaunchKernelGGL(k2_involution, dim3(16, 16, B_), dim3(256), 0, stream,
                       x, r_ws, wpp, b_span, out);
}

// Round 4
// 100.119 us; speedup vs baseline: 1.5594x; 1.0559x over previous
//
#include <hip/hip_runtime.h>
#include <hip/hip_bf16.h>
#include <stdint.h>

#define B_   4
#define H_   56
#define W_   56
#define C_   256
#define CR   64
#define G_   16
#define CG   16
#define KS   7
#define KK   49
#define PADR 3
#define NPX  (B_*H_*W_)   // 12544

typedef __attribute__((ext_vector_type(8))) short bf16x8;
typedef __attribute__((ext_vector_type(4))) float f32x4;
typedef __attribute__((ext_vector_type(2))) float f32x2;

__device__ __forceinline__ uint32_t f2bf(float f) {          // RNE fp32->bf16 bits
    uint32_t x = __float_as_uint(f);
    return (x + 0x7fffu + ((x >> 16) & 1u)) >> 16;
}
__device__ __forceinline__ uint32_t pkbf(float a, float b) { // packed RNE: v_cvt_pk_bf16_f32
    union { __hip_bfloat162 h; uint32_t u; } c;
    c.h = __float22bfloat162_rn(make_float2(a, b));
    return c.u;                                              // a in low 16, b in high 16
}
__device__ __forceinline__ float blo(uint32_t w) { return __uint_as_float(w << 16); }
__device__ __forceinline__ float bhi(uint32_t w) { return __uint_as_float(w & 0xffff0000u); }

union U4V { uint4 u; bf16x8 v; };

// ---------- K0: prepack weights into MFMA B-frag layout (bf16), fold BN ----------
// B-frag for mfma_f32_16x16x32_bf16: lane holds B[k=(lane>>4)*8+j][n=lane&15], j=0..7
__global__ __launch_bounds__(256) void k0_prepack(
        const float* __restrict__ wr, const float* __restrict__ wspan,
        const float* __restrict__ gamma, const float* __restrict__ beta,
        const float* __restrict__ mean, const float* __restrict__ var,
        uint16_t* __restrict__ wrp, uint16_t* __restrict__ wpp,
        float* __restrict__ scale, float* __restrict__ shift) {
    int idx = blockIdx.x * 256 + threadIdx.x;   // 0..65535
    {   // w_span pack: idx = g*4096 + kb*2048 + nb*512 + lane*8 + j
        int j = idx & 7, lane = (idx >> 3) & 63, nb = (idx >> 9) & 3,
            kb = (idx >> 11) & 1, g = idx >> 12;
        int k = kb * 32 + (lane >> 4) * 8 + j;
        int n = nb * 16 + (lane & 15);
        float v = (n < KK) ? wspan[k * (KK * G_) + g * KK + n] : 0.f;
        wpp[idx] = (uint16_t)f2bf(v);
    }
    if (idx < 16384) {  // w_reduce pack: idx = kb*2048 + nb*512 + lane*8 + j
        int j = idx & 7, lane = (idx >> 3) & 63, nb = (idx >> 9) & 3, kb = idx >> 11;
        int k = kb * 32 + (lane >> 4) * 8 + j;
        int n = nb * 16 + (lane & 15);
        wrp[idx] = (uint16_t)f2bf(wr[k * CR + n]);
    }
    if (idx < CR) {
        float s = gamma[idx] * rsqrtf(var[idx] + 1e-3f);
        scale[idx] = s;
        shift[idx] = beta[idx] - mean[idx] * s;
    }
}

// ---------- K1: r = relu(bn(x @ w_reduce)) via MFMA, r stored bf16 row-major ----------
__global__ __launch_bounds__(64) void k1_reduce(
        const float* __restrict__ x, const uint16_t* __restrict__ wrp,
        const float* __restrict__ scale, const float* __restrict__ shift,
        uint16_t* __restrict__ r) {
    int lane = threadIdx.x;
    int mt = blockIdx.x;                         // 784 row-tiles of 16 pixels
    int pix = mt * 16 + (lane & 15);             // A-frag: m = lane&15
    const float* xrow = x + (size_t)pix * C_ + (lane >> 4) * 8;
    f32x4 acc[4] = {{0,0,0,0},{0,0,0,0},{0,0,0,0},{0,0,0,0}};
    for (int kb = 0; kb < 8; ++kb) {             // K = 256 in steps of 32
        float4 a0 = *(const float4*)(xrow + kb * 32);
        float4 a1 = *(const float4*)(xrow + kb * 32 + 4);
        U4V af;
        af.u = make_uint4(pkbf(a0.x, a0.y), pkbf(a0.z, a0.w),
                          pkbf(a1.x, a1.y), pkbf(a1.z, a1.w));
        const uint16_t* wb = wrp + kb * 2048 + lane * 8;
        #pragma unroll
        for (int nb = 0; nb < 4; ++nb) {
            bf16x8 bf_ = *(const bf16x8*)(wb + nb * 512);
            acc[nb] = __builtin_amdgcn_mfma_f32_16x16x32_bf16(af.v, bf_, acc[nb], 0, 0, 0);
        }
    }
    // C layout: col=lane&15 (channel within nb), row=(lane>>4)*4+reg (pixel)
    int rq = (lane >> 4) * 4;
    #pragma unroll
    for (int nb = 0; nb < 4; ++nb) {
        int d = nb * 16 + (lane & 15);
        float s = scale[d], sh = shift[d];
        #pragma unroll
        for (int rg = 0; rg < 4; ++rg) {
            float v = fmaf(acc[nb][rg], s, sh);
            v = v > 0.f ? v : 0.f;
            r[(size_t)(mt * 16 + rq + rg) * CR + d] = (uint16_t)f2bf(v);
        }
    }
}

// ---------- K2: kgen (MFMA) + involution, one block per (tile, group, batch) ----------
#define TS   14          // output tile edge
#define HS   20          // TS + KS - 1
#define XSW  24          // u16 per LDS position slot (16 ch + 8 pad) = 48 B (16B-aligned)
#define XROW (21*XSW)    // 504 u16 per halo row (1008 B; 252 dwords == 28 mod 32 banks)
#define KGW  56          // u16 per kg row (49 taps + pad; 112 B, 16B-aligned)

__global__ __launch_bounds__(256, 3) void k2_involution(
        const float* __restrict__ x, const uint16_t* __restrict__ r,
        const uint16_t* __restrict__ wpp, const float* __restrict__ bspan,
        float* __restrict__ out) {
    __shared__ __align__(16) uint16_t xs[HS * XROW];   // 20160 B
    __shared__ __align__(16) uint16_t kg[208 * KGW];   // 23296 B  (43.5 KB -> 3 blocks/CU)

    int tid  = threadIdx.x;
    int tile = blockIdx.x, g = blockIdx.y, b = blockIdx.z;
    int ty0 = (tile >> 2) * TS, tx0 = (tile & 3) * TS;

    // ---- stage x group-slice (with halo) into LDS as bf16 ----
    #pragma unroll
    for (int pass = 0; pass < 2; ++pass) {
        int i = tid + pass * 256;
        if (i < HS * HS) {
            int py = i / HS, px = i % HS;
            int gy = ty0 + py - PADR, gx = tx0 + px - PADR;
            uint4 wA = make_uint4(0, 0, 0, 0), wB = wA;
            if (gy >= 0 && gy < H_ && gx >= 0 && gx < W_) {
                const float* xp = x + (((size_t)(b * H_ + gy)) * W_ + gx) * C_ + g * CG;
                float4 v0 = *(const float4*)(xp + 0);
                float4 v1 = *(const float4*)(xp + 4);
                float4 v2 = *(const float4*)(xp + 8);
                float4 v3 = *(const float4*)(xp + 12);
                wA = make_uint4(pkbf(v0.x, v0.y), pkbf(v0.z, v0.w),
                                pkbf(v1.x, v1.y), pkbf(v1.z, v1.w));
                wB = make_uint4(pkbf(v2.x, v2.y), pkbf(v2.z, v2.w),
                                pkbf(v3.x, v3.y), pkbf(v3.z, v3.w));
            }
            uint16_t* dst = xs + py * XROW + px * XSW;
            *(uint4*)(dst + 0) = wA;
            *(uint4*)(dst + 8) = wB;
        }
    }

    // ---- kgen via MFMA: kg(196x49) = r_tile(196x64) @ wspan_g(64x49) + bias ----
    int lane = tid & 63, w = tid >> 6;
    bf16x8 bfr[2][4];
    const uint16_t* wb = wpp + g * 4096 + lane * 8;
    #pragma unroll
    for (int kb = 0; kb < 2; ++kb)
        #pragma unroll
        for (int nb = 0; nb < 4; ++nb)
            bfr[kb][nb] = *(const bf16x8*)(wb + kb * 2048 + nb * 512);
    float bias[4];
    #pragma unroll
    for (int nb = 0; nb < 4; ++nb) {
        int n = nb * 16 + (lane & 15);
        bias[nb] = (n < KK) ? bspan[g * KK + n] : 0.f;
    }
    for (int mi = 0; mi < 4; ++mi) {
        int mt = mi * 4 + w;                    // 13 row-tiles over 4 waves
        if (mt < 13) {
            int m  = mt * 16 + (lane & 15);
            int mm = m < 196 ? m : 195;         // pad rows: valid mem, ignored later
            int ly = mm / TS, lx = mm % TS;
            size_t pix = ((size_t)(b * H_ + ty0 + ly)) * W_ + (tx0 + lx);
            const uint16_t* rp = r + pix * CR + (lane >> 4) * 8;
            bf16x8 a0 = *(const bf16x8*)(rp);
            bf16x8 a1 = *(const bf16x8*)(rp + 32);
            f32x4 acc[4];
            #pragma unroll
            for (int nb = 0; nb < 4; ++nb)
                acc[nb] = (f32x4){bias[nb], bias[nb], bias[nb], bias[nb]};
            #pragma unroll
            for (int nb = 0; nb < 4; ++nb) {
                acc[nb] = __builtin_amdgcn_mfma_f32_16x16x32_bf16(a0, bfr[0][nb], acc[nb], 0, 0, 0);
                acc[nb] = __builtin_amdgcn_mfma_f32_16x16x32_bf16(a1, bfr[1][nb], acc[nb], 0, 0, 0);
            }
            #pragma unroll
            for (int nb = 0; nb < 4; ++nb) {
                int n = nb * 16 + (lane & 15);
                if (n < KK) {
                    int row = mt * 16 + (lane >> 4) * 4;
                    #pragma unroll
                    for (int rg = 0; rg < 4; ++rg)
                        kg[(row + rg) * KGW + n] = (uint16_t)f2bf(acc[nb][rg]);
                }
            }
        }
    }
    __syncthreads();

    // ---- involution: 196 threads = (pixel-pair, 8-ch half); 2 adjacent px share xs reads ----
    if (tid < 196) {
        int p = tid >> 1, h = tid & 1;          // pair 0..97, channel half 0/1
        int ty = p / 7, tx = (p % 7) * 2;
        int rowL = ty * TS + tx;

        uint32_t kwL[28], kwR[28];              // 49 taps (bf16) per pixel, in regs
        #pragma unroll
        for (int t = 0; t < 7; ++t) {
            uint4 a = *(const uint4*)(kg + rowL * KGW + t * 8);
            uint4 c = *(const uint4*)(kg + (rowL + 1) * KGW + t * 8);
            kwL[t*4+0] = a.x; kwL[t*4+1] = a.y; kwL[t*4+2] = a.z; kwL[t*4+3] = a.w;
            kwR[t*4+0] = c.x; kwR[t*4+1] = c.y; kwR[t*4+2] = c.z; kwR[t*4+3] = c.w;
        }

        f32x2 accL[4] = {{0,0},{0,0},{0,0},{0,0}};
        f32x2 accR[4] = {{0,0},{0,0},{0,0},{0,0}};
        #pragma unroll
        for (int kh = 0; kh < KS; ++kh) {
            const uint16_t* xrow = xs + (ty + kh) * XROW + tx * XSW + h * 8;
            #pragma unroll
            for (int j = 0; j < 8; ++j) {       // union of both 7-tap windows
                uint4 xw = *(const uint4*)(xrow + j * XSW);   // 8 bf16 channels
                float kvL = 0.f, kvR = 0.f;
                if (j < 7) { int t = kh * 7 + j;     kvL = (t & 1) ? bhi(kwL[t>>1]) : blo(kwL[t>>1]); }
                if (j > 0) { int t = kh * 7 + j - 1; kvR = (t & 1) ? bhi(kwR[t>>1]) : blo(kwR[t>>1]); }
                f32x2 kL = {kvL, kvL}, kR = {kvR, kvR};
                f32x2 x0 = {blo(xw.x), bhi(xw.x)};
                f32x2 x1 = {blo(xw.y), bhi(xw.y)};
                f32x2 x2 = {blo(xw.z), bhi(xw.z)};
                f32x2 x3 = {blo(xw.w), bhi(xw.w)};
                accL[0] = __builtin_elementwise_fma(kL, x0, accL[0]);
                accL[1] = __builtin_elementwise_fma(kL, x1, accL[1]);
                accL[2] = __builtin_elementwise_fma(kL, x2, accL[2]);
                accL[3] = __builtin_elementwise_fma(kL, x3, accL[3]);
                accR[0] = __builtin_elementwise_fma(kR, x0, accR[0]);
                accR[1] = __builtin_elementwise_fma(kR, x1, accR[1]);
                accR[2] = __builtin_elementwise_fma(kR, x2, accR[2]);
                accR[3] = __builtin_elementwise_fma(kR, x3, accR[3]);
            }
        }
        size_t pixL = ((size_t)(b * H_ + ty0 + ty)) * W_ + (tx0 + tx);
        float* opL = out + pixL * C_ + g * CG + h * 8;
        float* opR = opL + C_;
        *(float4*)(opL + 0) = make_float4(accL[0].x, accL[0].y, accL[1].x, accL[1].y);
        *(float4*)(opL + 4) = make_float4(accL[2].x, accL[2].y, accL[3].x, accL[3].y);
        *(float4*)(opR + 0) = make_float4(accR[0].x, accR[0].y, accR[1].x, accR[1].y);
        *(float4*)(opR + 4) = make_float4(accR[2].x, accR[2].y, accR[3].x, accR[3].y);
    }
}

extern "C" void kernel_launch(void* const* d_in, const int* in_sizes, int n_in,
                              void* d_out, int out_size, void* d_ws, size_t ws_size,
                              hipStream_t stream) {
    const float* x        = (const float*)d_in[0];
    const float* w_reduce = (const float*)d_in[1];
    const float* gamma    = (const float*)d_in[2];
    const float* beta     = (const float*)d_in[3];
    const float* mean     = (const float*)d_in[4];
    const float* var      = (const float*)d_in[5];
    const float* w_span   = (const float*)d_in[6];
    const float* b_span   = (const float*)d_in[7];
    float* out = (float*)d_out;

    uint8_t* ws = (uint8_t*)d_ws;
    uint16_t* r_ws  = (uint16_t*)(ws + 0);          // 1605632 B
    uint16_t* wrp   = (uint16_t*)(ws + 1605632);    // 32768 B
    uint16_t* wpp   = (uint16_t*)(ws + 1638400);    // 131072 B
    float*    scale = (float*)   (ws + 1769472);    // 256 B
    float*    shift = (float*)   (ws + 1769728);    // 256 B

    hipLaunchKernelGGL(k0_prepack, dim3(256), dim3(256), 0, stream,
                       w_reduce, w_span, gamma, beta, mean, var,
                       wrp, wpp, scale, shift);
    hipLaunchKernelGGL(k1_reduce, dim3(NPX / 16), dim3(64), 0, stream,
                       x, wrp, scale, shift, r_ws);
    hipLaunchKernelGGL(k2_involution, dim3(16, 16, B_), dim3(256), 0, stream,
                       x, r_ws, wpp, b_span, out);
}

// Round 5
// 99.073 us; speedup vs baseline: 1.5759x; 1.0106x over previous
//
#include <hip/hip_runtime.h>
#include <hip/hip_bf16.h>
#include <stdint.h>

#define B_   4
#define H_   56
#define W_   56
#define C_   256
#define CR   64
#define G_   16
#define CG   16
#define KS   7
#define KK   49
#define PADR 3
#define NPX  (B_*H_*W_)   // 12544

typedef __attribute__((ext_vector_type(8))) short bf16x8;
typedef __attribute__((ext_vector_type(4))) float f32x4;
typedef __attribute__((ext_vector_type(2))) float f32x2;

__device__ __forceinline__ uint32_t f2bf(float f) {          // RNE fp32->bf16 bits
    uint32_t x = __float_as_uint(f);
    return (x + 0x7fffu + ((x >> 16) & 1u)) >> 16;
}
__device__ __forceinline__ uint32_t pkbf(float a, float b) { // packed RNE: v_cvt_pk_bf16_f32
    union { __hip_bfloat162 h; uint32_t u; } c;
    c.h = __float22bfloat162_rn(make_float2(a, b));
    return c.u;                                              // a lo16, b hi16
}
__device__ __forceinline__ float blo(uint32_t w) { return __uint_as_float(w << 16); }
__device__ __forceinline__ float bhi(uint32_t w) { return __uint_as_float(w & 0xffff0000u); }

union U4V { uint4 u; bf16x8 v; };

// ---------- K0: prepack weights into MFMA B-frag layout (bf16), fold BN ----------
// B-frag for mfma_f32_16x16x32_bf16: lane holds B[k=(lane>>4)*8+j][n=lane&15], j=0..7
__global__ __launch_bounds__(256) void k0_prepack(
        const float* __restrict__ wr, const float* __restrict__ wspan,
        const float* __restrict__ gamma, const float* __restrict__ beta,
        const float* __restrict__ mean, const float* __restrict__ var,
        uint16_t* __restrict__ wrp, uint16_t* __restrict__ wpp,
        float* __restrict__ scale, float* __restrict__ shift) {
    int idx = blockIdx.x * 256 + threadIdx.x;   // 0..65535
    {   // w_span pack: idx = g*4096 + kb*2048 + nb*512 + lane*8 + j
        int j = idx & 7, lane = (idx >> 3) & 63, nb = (idx >> 9) & 3,
            kb = (idx >> 11) & 1, g = idx >> 12;
        int k = kb * 32 + (lane >> 4) * 8 + j;
        int n = nb * 16 + (lane & 15);
        float v = (n < KK) ? wspan[k * (KK * G_) + g * KK + n] : 0.f;
        wpp[idx] = (uint16_t)f2bf(v);
    }
    if (idx < 16384) {  // w_reduce pack
        int j = idx & 7, lane = (idx >> 3) & 63, nb = (idx >> 9) & 3, kb = idx >> 11;
        int k = kb * 32 + (lane >> 4) * 8 + j;
        int n = nb * 16 + (lane & 15);
        wrp[idx] = (uint16_t)f2bf(wr[k * CR + n]);
    }
    if (idx < CR) {
        float s = gamma[idx] * rsqrtf(var[idx] + 1e-3f);
        scale[idx] = s;
        shift[idx] = beta[idx] - mean[idx] * s;
    }
}

// ---------- K1: r = relu(bn(x @ w_reduce)) via MFMA + emit x as bf16 ----------
__global__ __launch_bounds__(256) void k1_reduce(
        const float* __restrict__ x, const uint16_t* __restrict__ wrp,
        const float* __restrict__ scale, const float* __restrict__ shift,
        uint16_t* __restrict__ r, uint16_t* __restrict__ xbf) {
    int tid = threadIdx.x;
    int lane = tid & 63, w = tid >> 6;
    int mt = blockIdx.x * 4 + w;                 // 784 row-tiles of 16 pixels
    int pix = mt * 16 + (lane & 15);             // A-frag: m = lane&15
    int ko = (lane >> 4) * 8;                    // k-offset within 32-block
    const float* xrow = x + (size_t)pix * C_ + ko;
    f32x4 acc[4] = {{0,0,0,0},{0,0,0,0},{0,0,0,0},{0,0,0,0}};
    for (int kb = 0; kb < 8; ++kb) {             // K = 256 in steps of 32
        float4 a0 = *(const float4*)(xrow + kb * 32);
        float4 a1 = *(const float4*)(xrow + kb * 32 + 4);
        U4V af;
        af.u = make_uint4(pkbf(a0.x, a0.y), pkbf(a0.z, a0.w),
                          pkbf(a1.x, a1.y), pkbf(a1.z, a1.w));
        // bf16 copy of x for K2 staging (same values K2 used before)
        *(uint4*)(xbf + (size_t)pix * C_ + ko + kb * 32) = af.u;
        const uint16_t* wb = wrp + kb * 2048 + lane * 8;
        #pragma unroll
        for (int nb = 0; nb < 4; ++nb) {
            bf16x8 bf_ = *(const bf16x8*)(wb + nb * 512);
            acc[nb] = __builtin_amdgcn_mfma_f32_16x16x32_bf16(af.v, bf_, acc[nb], 0, 0, 0);
        }
    }
    // C layout: col=lane&15 (channel), row=(lane>>4)*4+reg (pixel)
    int rq = (lane >> 4) * 4;
    #pragma unroll
    for (int nb = 0; nb < 4; ++nb) {
        int d = nb * 16 + (lane & 15);
        float s = scale[d], sh = shift[d];
        #pragma unroll
        for (int rg = 0; rg < 4; ++rg) {
            float v = fmaf(acc[nb][rg], s, sh);
            v = v > 0.f ? v : 0.f;
            r[(size_t)(mt * 16 + rq + rg) * CR + d] = (uint16_t)f2bf(v);
        }
    }
}

// ---------- K2: kgen (MFMA) + involution, one block per (tile, group, batch) ----------
#define TS   14          // output tile edge
#define HS   20          // TS + KS - 1
#define XSW  16          // u16 per LDS position slot (16 ch, no pad; 32B slot, 16B aligned)
#define KGW  56          // u16 per kg row: 7 kh * 8 slots (7 taps + 1 pad) -> per-kh uint4 aligned

__global__ __launch_bounds__(256, 4) void k2_involution(
        const uint16_t* __restrict__ xbf, const uint16_t* __restrict__ r,
        const uint16_t* __restrict__ wpp, const float* __restrict__ bspan,
        float* __restrict__ out) {
    __shared__ __align__(16) uint16_t xs[HS * HS * XSW];   // 12800 B
    __shared__ __align__(16) uint16_t kg[196 * KGW];       // 21952 B  (34.75 KB -> 4 blocks/CU)

    int tid  = threadIdx.x;
    int tile = blockIdx.x, g = blockIdx.y, b = blockIdx.z;
    int ty0 = (tile >> 2) * TS, tx0 = (tile & 3) * TS;

    // ---- stage x group-slice (with halo) into LDS: raw bf16, no conversion ----
    #pragma unroll
    for (int pass = 0; pass < 2; ++pass) {
        int i = tid + pass * 256;
        if (i < HS * HS) {
            int py = i / HS, px = i % HS;
            int gy = ty0 + py - PADR, gx = tx0 + px - PADR;
            uint4 wA = make_uint4(0, 0, 0, 0), wB = wA;
            if (gy >= 0 && gy < H_ && gx >= 0 && gx < W_) {
                const uint16_t* xp = xbf + (((size_t)(b * H_ + gy)) * W_ + gx) * C_ + g * CG;
                wA = *(const uint4*)(xp);
                wB = *(const uint4*)(xp + 8);
            }
            uint16_t* dst = xs + i * XSW;        // contiguous: i*32 bytes
            *(uint4*)(dst + 0) = wA;
            *(uint4*)(dst + 8) = wB;
        }
    }

    // ---- kgen via MFMA: kg(196x49) = r_tile(196x64) @ wspan_g(64x49) + bias ----
    int lane = tid & 63, w = tid >> 6;
    bf16x8 bfr[2][4];
    const uint16_t* wb = wpp + g * 4096 + lane * 8;
    #pragma unroll
    for (int kb = 0; kb < 2; ++kb)
        #pragma unroll
        for (int nb = 0; nb < 4; ++nb)
            bfr[kb][nb] = *(const bf16x8*)(wb + kb * 2048 + nb * 512);
    float bias[4];
    #pragma unroll
    for (int nb = 0; nb < 4; ++nb) {
        int n = nb * 16 + (lane & 15);
        bias[nb] = (n < KK) ? bspan[g * KK + n] : 0.f;
    }
    for (int mi = 0; mi < 4; ++mi) {
        int mt = mi * 4 + w;                    // 13 row-tiles over 4 waves
        if (mt < 13) {
            int m  = mt * 16 + (lane & 15);
            int mm = m < 196 ? m : 195;         // pad rows: valid mem, ignored later
            int ly = mm / TS, lx = mm % TS;
            size_t pix = ((size_t)(b * H_ + ty0 + ly)) * W_ + (tx0 + lx);
            const uint16_t* rp = r + pix * CR + (lane >> 4) * 8;
            bf16x8 a0 = *(const bf16x8*)(rp);
            bf16x8 a1 = *(const bf16x8*)(rp + 32);
            f32x4 acc[4];
            #pragma unroll
            for (int nb = 0; nb < 4; ++nb)
                acc[nb] = (f32x4){bias[nb], bias[nb], bias[nb], bias[nb]};
            #pragma unroll
            for (int nb = 0; nb < 4; ++nb) {
                acc[nb] = __builtin_amdgcn_mfma_f32_16x16x32_bf16(a0, bfr[0][nb], acc[nb], 0, 0, 0);
                acc[nb] = __builtin_amdgcn_mfma_f32_16x16x32_bf16(a1, bfr[1][nb], acc[nb], 0, 0, 0);
            }
            int row = mt * 16 + (lane >> 4) * 4;
            if (row < 196) {                    // skip pad rows entirely
                #pragma unroll
                for (int nb = 0; nb < 4; ++nb) {
                    int n = nb * 16 + (lane & 15);
                    if (n < KK) {
                        int slot = n + n / 7;   // per-kh padded: kh*8 + kw
                        #pragma unroll
                        for (int rg = 0; rg < 4; ++rg)
                            kg[(row + rg) * KGW + slot] = (uint16_t)f2bf(acc[nb][rg]);
                    }
                }
            }
        }
    }
    __syncthreads();

    // ---- involution: 196 threads = (pixel-pair, 8-ch half); adjacent px share xs reads ----
    if (tid < 196) {
        int p = tid >> 1, h = tid & 1;          // pair 0..97, channel half 0/1
        int ty = p / 7, tx = (p % 7) * 2;
        const uint16_t* kgL = kg + (ty * TS + tx) * KGW;
        const uint16_t* kgR = kgL + KGW;

        f32x2 accL[4] = {{0,0},{0,0},{0,0},{0,0}};
        f32x2 accR[4] = {{0,0},{0,0},{0,0},{0,0}};
        #pragma unroll
        for (int kh = 0; kh < KS; ++kh) {
            uint4 aL = *(const uint4*)(kgL + kh * 8);   // taps kh*7..kh*7+6 (+pad)
            uint4 aR = *(const uint4*)(kgR + kh * 8);
            const uint32_t kwL[4] = {aL.x, aL.y, aL.z, aL.w};
            const uint32_t kwR[4] = {aR.x, aR.y, aR.z, aR.w};
            const uint16_t* xrow = xs + ((ty + kh) * HS + tx) * XSW + h * 8;
            #pragma unroll
            for (int j = 0; j < 8; ++j) {       // union of both 7-tap windows
                uint4 xw = *(const uint4*)(xrow + j * XSW);   // 8 bf16 channels
                float kvL = 0.f, kvR = 0.f;
                if (j < 7) kvL = (j & 1) ? bhi(kwL[j >> 1]) : blo(kwL[j >> 1]);
                if (j > 0) { int t = j - 1; kvR = (t & 1) ? bhi(kwR[t >> 1]) : blo(kwR[t >> 1]); }
                f32x2 kL = {kvL, kvL}, kR = {kvR, kvR};
                f32x2 x0 = {blo(xw.x), bhi(xw.x)};
                f32x2 x1 = {blo(xw.y), bhi(xw.y)};
                f32x2 x2 = {blo(xw.z), bhi(xw.z)};
                f32x2 x3 = {blo(xw.w), bhi(xw.w)};
                accL[0] = __builtin_elementwise_fma(kL, x0, accL[0]);
                accL[1] = __builtin_elementwise_fma(kL, x1, accL[1]);
                accL[2] = __builtin_elementwise_fma(kL, x2, accL[2]);
                accL[3] = __builtin_elementwise_fma(kL, x3, accL[3]);
                accR[0] = __builtin_elementwise_fma(kR, x0, accR[0]);
                accR[1] = __builtin_elementwise_fma(kR, x1, accR[1]);
                accR[2] = __builtin_elementwise_fma(kR, x2, accR[2]);
                accR[3] = __builtin_elementwise_fma(kR, x3, accR[3]);
            }
        }
        size_t pixL = ((size_t)(b * H_ + ty0 + ty)) * W_ + (tx0 + tx);
        float* opL = out + pixL * C_ + g * CG + h * 8;
        float* opR = opL + C_;
        *(float4*)(opL + 0) = make_float4(accL[0].x, accL[0].y, accL[1].x, accL[1].y);
        *(float4*)(opL + 4) = make_float4(accL[2].x, accL[2].y, accL[3].x, accL[3].y);
        *(float4*)(opR + 0) = make_float4(accR[0].x, accR[0].y, accR[1].x, accR[1].y);
        *(float4*)(opR + 4) = make_float4(accR[2].x, accR[2].y, accR[3].x, accR[3].y);
    }
}

extern "C" void kernel_launch(void* const* d_in, const int* in_sizes, int n_in,
                              void* d_out, int out_size, void* d_ws, size_t ws_size,
                              hipStream_t stream) {
    const float* x        = (const float*)d_in[0];
    const float* w_reduce = (const float*)d_in[1];
    const float* gamma    = (const float*)d_in[2];
    const float* beta     = (const float*)d_in[3];
    const float* mean     = (const float*)d_in[4];
    const float* var      = (const float*)d_in[5];
    const float* w_span   = (const float*)d_in[6];
    const float* b_span   = (const float*)d_in[7];
    float* out = (float*)d_out;

    uint8_t* ws = (uint8_t*)d_ws;
    uint16_t* r_ws  = (uint16_t*)(ws + 0);          // 1605632 B
    uint16_t* wrp   = (uint16_t*)(ws + 1605632);    // 32768 B
    uint16_t* wpp   = (uint16_t*)(ws + 1638400);    // 131072 B
    float*    scale = (float*)   (ws + 1769472);    // 256 B
    float*    shift = (float*)   (ws + 1769728);    // 256 B
    uint16_t* xbf   = (uint16_t*)(ws + 1769984);    // 6422528 B

    hipLaunchKernelGGL(k0_prepack, dim3(256), dim3(256), 0, stream,
                       w_reduce, w_span, gamma, beta, mean, var,
                       wrp, wpp, scale, shift);
    hipLaunchKernelGGL(k1_reduce, dim3(NPX / 64), dim3(256), 0, stream,
                       x, wrp, scale, shift, r_ws, xbf);
    hipLaunchKernelGGL(k2_involution, dim3(16, 16, B_), dim3(256), 0, stream,
                       xbf, r_ws, wpp, b_span, out);
}